// Round 13
// baseline (106.484 us; speedup 1.0000x reference)
//
#include <hip/hip_runtime.h>
#include <hip/hip_bf16.h>
#include <hip/hip_fp8.h>

constexpr int N    = 50000;
constexpr int NPAD = 50048;          // padded to 64-row tiles (782*64)
constexpr int FIN  = 128;
constexpr int HID  = 256;
constexpr int NC   = 16;
constexpr int NE   = 600000;
constexpr int CAP  = 64;             // per-node bucket capacity (max deg ~40)
constexpr int CASTB = (NPAD * FIN / 8) / 256;   // 3128 cast blocks (exact)

using bf16x8 = __attribute__((ext_vector_type(8))) short;
using f32x4  = __attribute__((ext_vector_type(4))) float;
using f32x2  = __attribute__((ext_vector_type(2))) float;

#if defined(__has_builtin)
#  if __has_builtin(__builtin_amdgcn_cvt_pk_f32_fp8)
#    define PK_DEC 1
#  endif
#  if __has_builtin(__builtin_amdgcn_cvt_pk_fp8_f32)
#    define PK_ENC 1
#  endif
#endif

__device__ inline float bf2f(unsigned short u) {
    union { unsigned int i; float f; } v; v.i = (unsigned)u << 16; return v.f;
}
__device__ inline unsigned short f2bf(float f) {
    __hip_bfloat16 h = __float2bfloat16(f);
    return __builtin_bit_cast(unsigned short, h);
}
__device__ inline unsigned char f2f8(float f) {
    __hip_fp8_e4m3 h(f);
    return (unsigned char)h.__x;
}
__device__ inline float f82f(unsigned char u) {
    __hip_fp8_e4m3 h;
    h.__x = (__hip_fp8_storage_t)u;
    return (float)h;
}

// decode 16 fp8 (uint4) and accumulate into acc[16]
__device__ inline void acc16_fp8(float* acc, uint4 v) {
#ifdef PK_DEC
    const unsigned uu[4] = {v.x, v.y, v.z, v.w};
#pragma unroll
    for (int w = 0; w < 4; ++w) {
        f32x2 lo = __builtin_amdgcn_cvt_pk_f32_fp8((int)uu[w], false);
        f32x2 hi = __builtin_amdgcn_cvt_pk_f32_fp8((int)uu[w], true);
        acc[w * 4 + 0] += lo[0]; acc[w * 4 + 1] += lo[1];
        acc[w * 4 + 2] += hi[0]; acc[w * 4 + 3] += hi[1];
    }
#else
    const unsigned char* p = (const unsigned char*)&v;
#pragma unroll
    for (int k = 0; k < 16; ++k) acc[k] += f82f(p[k]);
#endif
}

// ---------------------------------------------------------------------------
// k_prep: blocks [0,CASTB) cast x->xb (bf16) AND x->xf8 (e4m3), pad zeroed;
//         blocks [CASTB, CASTB+232) pack W1/W2 + zero cnt[].
// ---------------------------------------------------------------------------
__global__ __launch_bounds__(256) void k_prep(const float* __restrict__ x,
                                              unsigned short* __restrict__ xb,
                                              unsigned char* __restrict__ xf8,
                                              const float* __restrict__ Wl,
                                              const float* __restrict__ Wr,
                                              const float* __restrict__ W2l,
                                              const float* __restrict__ W2r,
                                              unsigned short* __restrict__ Wlp,
                                              unsigned short* __restrict__ Wrp,
                                              unsigned short* __restrict__ Wc2p,
                                              unsigned* __restrict__ cnt) {
    if (blockIdx.x < (unsigned)CASTB) {
        size_t idx = (size_t)blockIdx.x * 256u + threadIdx.x;   // < NPAD*FIN/8
        bf16x8 o;
        uint2 e8 = {0u, 0u};
        if (idx < (size_t)N * FIN / 8) {
            const float4 v0 = *reinterpret_cast<const float4*>(&x[idx * 8]);
            const float4 v1 = *reinterpret_cast<const float4*>(&x[idx * 8 + 4]);
            o[0] = (short)f2bf(v0.x); o[1] = (short)f2bf(v0.y);
            o[2] = (short)f2bf(v0.z); o[3] = (short)f2bf(v0.w);
            o[4] = (short)f2bf(v1.x); o[5] = (short)f2bf(v1.y);
            o[6] = (short)f2bf(v1.z); o[7] = (short)f2bf(v1.w);
#ifdef PK_ENC
            int p0 = __builtin_amdgcn_cvt_pk_fp8_f32(v0.x, v0.y, 0, false);
            p0     = __builtin_amdgcn_cvt_pk_fp8_f32(v0.z, v0.w, p0, true);
            int p1 = __builtin_amdgcn_cvt_pk_fp8_f32(v1.x, v1.y, 0, false);
            p1     = __builtin_amdgcn_cvt_pk_fp8_f32(v1.z, v1.w, p1, true);
            e8.x = (unsigned)p0; e8.y = (unsigned)p1;
#else
            unsigned char b[8];
            b[0] = f2f8(v0.x); b[1] = f2f8(v0.y); b[2] = f2f8(v0.z); b[3] = f2f8(v0.w);
            b[4] = f2f8(v1.x); b[5] = f2f8(v1.y); b[6] = f2f8(v1.z); b[7] = f2f8(v1.w);
            e8 = *reinterpret_cast<uint2*>(b);
#endif
        } else {
            o = (bf16x8){0, 0, 0, 0, 0, 0, 0, 0};
        }
        *reinterpret_cast<bf16x8*>(&xb[idx * 8]) = o;
        *reinterpret_cast<uint2*>(&xf8[idx * 8]) = e8;
        return;
    }
    unsigned id = (blockIdx.x - CASTB) * 256u + threadIdx.x;    // < 59392
    if (id < 8192) {
        unsigned mat = id >> 12, kk = (id >> 10) & 3, c = (id >> 2) & 255, g = id & 3;
        const float* src = mat ? Wr : Wl;
        unsigned short* dst = mat ? Wrp : Wlp;
        bf16x8 o;
#pragma unroll
        for (int b = 0; b < 8; ++b)
            o[b] = (short)f2bf(src[(kk * 32 + g * 8 + b) * HID + c]);
        *reinterpret_cast<bf16x8*>(&dst[((kk * 256u + c) * 4u + g) * 8u]) = o;
    } else if (id < 9216) {
        unsigned id2 = id - 8192;                     // 1024: 8kk x 32cc x 4g
        unsigned kk = id2 >> 7, cc = (id2 >> 2) & 31, g = id2 & 3;
        bf16x8 o;
#pragma unroll
        for (int b = 0; b < 8; ++b) {
            unsigned k = kk * 32 + g * 8 + b;
            float v = (cc < 16) ? W2l[k * NC + cc] : W2r[k * NC + (cc - 16)];
            o[b] = (short)f2bf(v);
        }
        *reinterpret_cast<bf16x8*>(&Wc2p[((kk * 32u + cc) * 4u + g) * 8u]) = o;
    } else if (id - 9216 < (unsigned)N) {
        cnt[id - 9216] = 0u;
    }
}

// ---------------------------------------------------------------------------
// Bucket build: slot = cnt[dst]++, buck[dst*CAP+slot] = src (CAP-guarded).
// ---------------------------------------------------------------------------
__global__ __launch_bounds__(256) void k_bucket(const int* __restrict__ srcv,
                                                const int* __restrict__ dstv,
                                                unsigned* __restrict__ cnt,
                                                int* __restrict__ buck) {
    unsigned e = blockIdx.x * 256u + threadIdx.x;
    if (e >= (unsigned)NE) return;
    int d = dstv[e];
    unsigned slot = atomicAdd(&cnt[d], 1u);
    if (slot < (unsigned)CAP) buck[(size_t)d * CAP + slot] = srcv[e];
}

// ---------------------------------------------------------------------------
// Layer-1 aggregation (gather) over the fp8 table: one wave per node.
// grp = lane>>3 picks 1 of 8 edges per round, co = lane&7 picks a 16B chunk
// (16 fp8 cols). One uint4 load covers 8 edges' rows (deg-12: 2 loads).
// f32 accumulate; cross-edge reduce via shfl_xor 8/16/32; lanes 0-7 write
// the 256B bf16 agg row. Pad waves write zero rows.
// ---------------------------------------------------------------------------
__global__ __launch_bounds__(256) void k_agg1(const unsigned char* __restrict__ xf8,
                                              const int* __restrict__ buck,
                                              const unsigned* __restrict__ cnt,
                                              unsigned short* __restrict__ aggb) {
    const unsigned wid  = (blockIdx.x * 256u + threadIdx.x) >> 6;
    const unsigned lane = threadIdx.x & 63;
    const unsigned grp  = lane >> 3;      // edge-in-octet
    const unsigned co   = lane & 7;       // 16B chunk (16 fp8)
    if (wid >= (unsigned)N) {
        if (wid < (unsigned)NPAD && lane < 16)
            *reinterpret_cast<bf16x8*>(&aggb[(size_t)wid * FIN + lane * 8]) =
                (bf16x8){0, 0, 0, 0, 0, 0, 0, 0};
        return;
    }
    const unsigned cv  = cnt[wid];
    const unsigned deg = min(cv, (unsigned)CAP);
    const int eid = (lane < deg) ? buck[(size_t)wid * CAP + lane] : 0;

    float acc[16];
#pragma unroll
    for (int q = 0; q < 16; ++q) acc[q] = 0.f;

    unsigned j = 0;
    for (; j + 8 <= deg; j += 8) {
        const int s = __shfl(eid, (int)(j + grp), 64);
        const uint4 v = *reinterpret_cast<const uint4*>(&xf8[(size_t)s * FIN + co * 16]);
        acc16_fp8(acc, v);
    }
    if (j < deg) {                        // tail: <8 edges, one guarded load
        const int s = __shfl(eid, (int)(j + grp), 64);   // j+grp <= 63
        if (j + grp < deg) {
            const uint4 v = *reinterpret_cast<const uint4*>(&xf8[(size_t)s * FIN + co * 16]);
            acc16_fp8(acc, v);
        }
    }

    // reduce across the 8 edge-groups (lanes l, l^8, l^16, ..., l^56)
#pragma unroll
    for (int q = 0; q < 16; ++q) {
        acc[q] += __shfl_xor(acc[q], 8, 64);
        acc[q] += __shfl_xor(acc[q], 16, 64);
        acc[q] += __shfl_xor(acc[q], 32, 64);
    }

    if (lane < 8) {
        const float sc = 1.0f / fmaxf((float)cv, 1.0f);
        bf16x8 o0, o1;
#pragma unroll
        for (int q = 0; q < 8; ++q) {
            o0[q] = (short)f2bf(acc[q] * sc);
            o1[q] = (short)f2bf(acc[q + 8] * sc);
        }
        *reinterpret_cast<bf16x8*>(&aggb[(size_t)wid * FIN + co * 16]) = o0;
        *reinterpret_cast<bf16x8*>(&aggb[(size_t)wid * FIN + co * 16 + 8]) = o1;
    }
}

// ---------------------------------------------------------------------------
// Fused layer-1 GEMM + layer-2 pre-multiply, 64x256 tile, 256 threads.
// h1 never touches global memory.
// ---------------------------------------------------------------------------
__global__ __launch_bounds__(256) void k_l1m(const unsigned short* __restrict__ aggb,
                                             const unsigned short* __restrict__ xb,
                                             const unsigned short* __restrict__ Wlp,
                                             const unsigned short* __restrict__ Wrp,
                                             const unsigned short* __restrict__ Wc2p,
                                             const float* __restrict__ b1,
                                             float* __restrict__ y2,
                                             float* __restrict__ z2) {
    __shared__ short sA[2][64 * FIN];     // 32 KB; reused as sH[64][256] in stage 2
    short* sH = &sA[0][0];
    const int t = threadIdx.x;
    const int wave = t >> 6, lane = t & 63;
    const int g = lane >> 4, lr = lane & 15;
    const size_t row0 = (size_t)blockIdx.x * 64;

    for (int mat = 0; mat < 2; ++mat) {
        const unsigned short* src = mat ? xb : aggb;
        for (int i = t; i < 64 * 16; i += 256) {
            int r = i >> 4, c = i & 15;
            bf16x8 v = *reinterpret_cast<const bf16x8*>(&src[(row0 + r) * FIN + c * 8]);
            int dc = c ^ (r & 7);
            *reinterpret_cast<bf16x8*>(&sA[mat][r * FIN + dc * 8]) = v;
        }
    }
    __syncthreads();

    f32x4 acc[4][4];
#pragma unroll
    for (int m = 0; m < 4; ++m)
#pragma unroll
        for (int n = 0; n < 4; ++n) acc[m][n] = (f32x4){0.f, 0.f, 0.f, 0.f};

#pragma unroll
    for (int kk = 0; kk < 4; ++kk) {
        bf16x8 bL[4], bR[4];
#pragma unroll
        for (int n = 0; n < 4; ++n) {
            int col = wave * 64 + n * 16 + lr;
            size_t off = ((size_t)(kk * 256 + col) * 4 + g) * 8;
            bL[n] = *reinterpret_cast<const bf16x8*>(&Wlp[off]);
            bR[n] = *reinterpret_cast<const bf16x8*>(&Wrp[off]);
        }
        bf16x8 aA[4], aX[4];
        const int chunk = (kk * 4 + g) ^ (lr & 7);
#pragma unroll
        for (int m = 0; m < 4; ++m) {
            int r = m * 16 + lr;
            aA[m] = *reinterpret_cast<const bf16x8*>(&sA[0][r * FIN + chunk * 8]);
            aX[m] = *reinterpret_cast<const bf16x8*>(&sA[1][r * FIN + chunk * 8]);
        }
#pragma unroll
        for (int m = 0; m < 4; ++m)
#pragma unroll
            for (int n = 0; n < 4; ++n) {
                acc[m][n] = __builtin_amdgcn_mfma_f32_16x16x32_bf16(aA[m], bL[n], acc[m][n], 0, 0, 0);
                acc[m][n] = __builtin_amdgcn_mfma_f32_16x16x32_bf16(aX[m], bR[n], acc[m][n], 0, 0, 0);
            }
    }

    // stage 1 -> LDS: relu(acc+b1) as bf16, swizzled 16B chunks.
    __syncthreads();   // sA reads done in all waves
#pragma unroll
    for (int n = 0; n < 4; ++n) {
        int col = wave * 64 + n * 16 + lr;      // col&7 == lr&7
        float bb = b1[col];
        int c = col >> 3;
#pragma unroll
        for (int m = 0; m < 4; ++m) {
#pragma unroll
            for (int reg = 0; reg < 4; ++reg) {
                int r = m * 16 + g * 4 + reg;
                float z = fmaxf(acc[m][n][reg] + bb, 0.f);
                sH[r * HID + (c ^ (r & 7)) * 8 + (col & 7)] = (short)f2bf(z);
            }
        }
    }
    __syncthreads();

    // stage 2: rows [16*wave, 16*wave+16); k = 256; cols 0-15 Y, 16-31 Z.
    f32x4 accY = (f32x4){0.f, 0.f, 0.f, 0.f};
    f32x4 accZ = (f32x4){0.f, 0.f, 0.f, 0.f};
#pragma unroll
    for (int kk = 0; kk < 8; ++kk) {
        const int row = wave * 16 + lr;         // row&7 == lr&7
        const int dc = (kk * 4 + g) ^ (lr & 7);
        bf16x8 a  = *reinterpret_cast<const bf16x8*>(&sH[row * HID + dc * 8]);
        bf16x8 bY = *reinterpret_cast<const bf16x8*>(&Wc2p[((kk * 32u + lr) * 4u + g) * 8u]);
        bf16x8 bZ = *reinterpret_cast<const bf16x8*>(&Wc2p[((kk * 32u + 16u + lr) * 4u + g) * 8u]);
        accY = __builtin_amdgcn_mfma_f32_16x16x32_bf16(a, bY, accY, 0, 0, 0);
        accZ = __builtin_amdgcn_mfma_f32_16x16x32_bf16(a, bZ, accZ, 0, 0, 0);
    }
#pragma unroll
    for (int reg = 0; reg < 4; ++reg) {
        size_t r = row0 + wave * 16 + g * 4 + reg;
        y2[r * NC + lr] = accY[reg];
        z2[r * NC + lr] = accZ[reg];
    }
}

// ---------------------------------------------------------------------------
// out = log_softmax(gather(y2)/deg + z2 + b2); 16 lanes per node.
// Bucket ids, 16-wide coalesced; y2 row loads issued 8/4-deep.
// ---------------------------------------------------------------------------
__global__ __launch_bounds__(256) void k_out2(const float* __restrict__ y2,
                                              const float* __restrict__ z2,
                                              const int* __restrict__ buck,
                                              const unsigned* __restrict__ cnt,
                                              const float* __restrict__ b,
                                              float* __restrict__ out) {
    const int t = threadIdx.x, c = t & 15, nl = t >> 4;
    const int lbase = (nl & 3) * 16;          // lane offset of this 16-group in wave
    const size_t n = (size_t)blockIdx.x * 16 + nl;
    const unsigned cv  = cnt[n];
    const unsigned deg = min(cv, (unsigned)CAP);
    float gsum = 0.f;

    for (unsigned base = 0; base < deg; base += 16) {
        const unsigned cc = min(16u, deg - base);
        const int eid = ((unsigned)c < cc) ? buck[n * CAP + base + c] : 0;
        unsigned j = 0;
        for (; j + 8 <= cc; j += 8) {
            int s[8];
#pragma unroll
            for (int q = 0; q < 8; ++q) s[q] = __shfl(eid, lbase + (int)j + q, 64);
            float gv[8];
#pragma unroll
            for (int q = 0; q < 8; ++q) gv[q] = y2[(size_t)s[q] * NC + c];
#pragma unroll
            for (int q = 0; q < 8; ++q) gsum += gv[q];
        }
        for (; j + 4 <= cc; j += 4) {
            int s[4];
#pragma unroll
            for (int q = 0; q < 4; ++q) s[q] = __shfl(eid, lbase + (int)j + q, 64);
            float gv[4];
#pragma unroll
            for (int q = 0; q < 4; ++q) gv[q] = y2[(size_t)s[q] * NC + c];
#pragma unroll
            for (int q = 0; q < 4; ++q) gsum += gv[q];
        }
        for (; j < cc; ++j) {
            const int s = __shfl(eid, lbase + (int)j, 64);
            gsum += y2[(size_t)s * NC + c];
        }
    }
    const float sc = 1.0f / fmaxf((float)cv, 1.0f);
    float z = gsum * sc + z2[n * NC + c] + b[c];

    float m = z;
    for (int off = 1; off < 16; off <<= 1)
        m = fmaxf(m, __shfl_xor(m, off, 16));
    float ex = expf(z - m);
    float s = ex;
    for (int off = 1; off < 16; off <<= 1)
        s += __shfl_xor(s, off, 16);
    out[n * NC + c] = (z - m) - logf(s);
}

// ---------------------------------------------------------------------------
extern "C" void kernel_launch(void* const* d_in, const int* in_sizes, int n_in,
                              void* d_out, int out_size, void* d_ws, size_t ws_size,
                              hipStream_t stream) {
    const float* x    = (const float*)d_in[0];
    const int*   ei   = (const int*)d_in[1];    // int32 on device (JAX x64 off)
    const int*   srcv = ei;
    const int*   dstv = ei + NE;
    const float* W1l  = (const float*)d_in[2];
    const float* W1r  = (const float*)d_in[3];
    const float* b1   = (const float*)d_in[4];
    const float* W2l  = (const float*)d_in[5];
    const float* W2r  = (const float*)d_in[6];
    const float* b2   = (const float*)d_in[7];
    float* out = (float*)d_out;

    // workspace layout (float offsets; 16B alignment for vector users)
    float*          ws   = (float*)d_ws;
    unsigned*       cnt  = (unsigned*)ws;                     //    50,000
    int*            buck = (int*)(ws + 50000);                // 3,200,000 (N*CAP)
    unsigned short* xb   = (unsigned short*)(ws + 3250000);   // NPAD*128 bf16 = 3,203,072 f
    unsigned short* aggb = (unsigned short*)(ws + 6453072);   // NPAD*128 bf16
    unsigned char*  xf8  = (unsigned char*)(ws + 9656144);    // NPAD*128 fp8 = 1,601,536 f
    unsigned short* Wlp  = (unsigned short*)(ws + 11257680);  // 32768 bf16 = 16,384 f
    unsigned short* Wrp  = (unsigned short*)(ws + 11274064);  // 32768 bf16
    unsigned short* Wc2p = (unsigned short*)(ws + 11290448);  //  8192 bf16 =  4,096 f
    float*          y2   = ws + 11294544;                     // NPAD*16 = 800,768
    float*          z2   = ws + 12095312;                     // NPAD*16 = 800,768
    // total: 12,896,080 floats = 51.6 MB

    const int EB = (NE + 255) / 256;
    k_prep  <<<CASTB + 232, 256, 0, stream>>>(x, xb, xf8, W1l, W1r, W2l, W2r,
                                              Wlp, Wrp, Wc2p, cnt);
    k_bucket<<<EB, 256, 0, stream>>>(srcv, dstv, cnt, buck);
    k_agg1  <<<(NPAD * 64) / 256, 256, 0, stream>>>(xf8, buck, cnt, aggb);
    k_l1m   <<<NPAD / 64, 256, 0, stream>>>(aggb, xb, Wlp, Wrp, Wc2p, b1, y2, z2);
    k_out2  <<<N / 16, 256, 0, stream>>>(y2, z2, buck, cnt, b2, out);
}

// Round 15
// 103.731 us; speedup vs baseline: 1.0265x; 1.0265x over previous
//
#include <hip/hip_runtime.h>
#include <hip/hip_bf16.h>

constexpr int N    = 50000;
constexpr int NPAD = 50048;          // padded to 64-row tiles (782*64)
constexpr int FIN  = 128;
constexpr int HID  = 256;
constexpr int NC   = 16;
constexpr int NE   = 600000;
constexpr int CAP  = 64;             // per-node bucket capacity (max deg ~34)
constexpr int CASTB = (NPAD * FIN / 8) / 256;   // 3128 cast blocks (exact)

using bf16x8 = __attribute__((ext_vector_type(8))) short;
using f32x4  = __attribute__((ext_vector_type(4))) float;

__device__ inline float bf2f(unsigned short u) {
    union { unsigned int i; float f; } v; v.i = (unsigned)u << 16; return v.f;
}
__device__ inline unsigned short f2bf(float f) {
    __hip_bfloat16 h = __float2bfloat16(f);
    return __builtin_bit_cast(unsigned short, h);
}

// ---------------------------------------------------------------------------
// k_prep: blocks [0,CASTB) cast x->xb (pad rows zeroed);
//         blocks [CASTB, CASTB+232) pack W1/W2 + zero cnt[].
// ---------------------------------------------------------------------------
__global__ __launch_bounds__(256) void k_prep(const float* __restrict__ x,
                                              unsigned short* __restrict__ xb,
                                              const float* __restrict__ Wl,
                                              const float* __restrict__ Wr,
                                              const float* __restrict__ W2l,
                                              const float* __restrict__ W2r,
                                              unsigned short* __restrict__ Wlp,
                                              unsigned short* __restrict__ Wrp,
                                              unsigned short* __restrict__ Wc2p,
                                              unsigned* __restrict__ cnt) {
    if (blockIdx.x < (unsigned)CASTB) {
        size_t idx = (size_t)blockIdx.x * 256u + threadIdx.x;   // < NPAD*FIN/8
        bf16x8 o;
        if (idx < (size_t)N * FIN / 8) {
            const float4 v0 = *reinterpret_cast<const float4*>(&x[idx * 8]);
            const float4 v1 = *reinterpret_cast<const float4*>(&x[idx * 8 + 4]);
            o[0] = (short)f2bf(v0.x); o[1] = (short)f2bf(v0.y);
            o[2] = (short)f2bf(v0.z); o[3] = (short)f2bf(v0.w);
            o[4] = (short)f2bf(v1.x); o[5] = (short)f2bf(v1.y);
            o[6] = (short)f2bf(v1.z); o[7] = (short)f2bf(v1.w);
        } else {
            o = (bf16x8){0, 0, 0, 0, 0, 0, 0, 0};
        }
        *reinterpret_cast<bf16x8*>(&xb[idx * 8]) = o;
        return;
    }
    unsigned id = (blockIdx.x - CASTB) * 256u + threadIdx.x;    // < 59392
    if (id < 8192) {
        unsigned mat = id >> 12, kk = (id >> 10) & 3, c = (id >> 2) & 255, g = id & 3;
        const float* src = mat ? Wr : Wl;
        unsigned short* dst = mat ? Wrp : Wlp;
        bf16x8 o;
#pragma unroll
        for (int b = 0; b < 8; ++b)
            o[b] = (short)f2bf(src[(kk * 32 + g * 8 + b) * HID + c]);
        *reinterpret_cast<bf16x8*>(&dst[((kk * 256u + c) * 4u + g) * 8u]) = o;
    } else if (id < 9216) {
        unsigned id2 = id - 8192;                     // 1024: 8kk x 32cc x 4g
        unsigned kk = id2 >> 7, cc = (id2 >> 2) & 31, g = id2 & 3;
        bf16x8 o;
#pragma unroll
        for (int b = 0; b < 8; ++b) {
            unsigned k = kk * 32 + g * 8 + b;
            float v = (cc < 16) ? W2l[k * NC + cc] : W2r[k * NC + (cc - 16)];
            o[b] = (short)f2bf(v);
        }
        *reinterpret_cast<bf16x8*>(&Wc2p[((kk * 32u + cc) * 4u + g) * 8u]) = o;
    } else if (id - 9216 < (unsigned)N) {
        cnt[id - 9216] = 0u;
    }
}

// ---------------------------------------------------------------------------
// Bucket build: slot = cnt[dst]++, buck[dst*CAP+slot] = src (CAP-guarded).
// ---------------------------------------------------------------------------
__global__ __launch_bounds__(256) void k_bucket(const int* __restrict__ srcv,
                                                const int* __restrict__ dstv,
                                                unsigned* __restrict__ cnt,
                                                int* __restrict__ buck) {
    unsigned e = blockIdx.x * 256u + threadIdx.x;
    if (e >= (unsigned)NE) return;
    int d = dstv[e];
    unsigned slot = atomicAdd(&cnt[d], 1u);
    if (slot < (unsigned)CAP) buck[(size_t)d * CAP + slot] = srcv[e];
}

// ---------------------------------------------------------------------------
// Layer-1 aggregation (gather): one wave per node.
// Lane layout: grp = lane>>4 picks 1 of 4 edges, co = lane&15 picks a 16B
// chunk -> ONE bf16x8 load covers 4 edges' rows. deg<=64: main loop does
// 8 edges per iter (2 independent loads); guarded tail does up to 8 more.
// Cross-edge reduce: shfl_xor 16/32; lanes 0-15 write 256B.
// ---------------------------------------------------------------------------
__global__ __launch_bounds__(256) void k_agg1(const unsigned short* __restrict__ xb,
                                              const int* __restrict__ buck,
                                              const unsigned* __restrict__ cnt,
                                              unsigned short* __restrict__ aggb) {
    const unsigned wid  = (blockIdx.x * 256u + threadIdx.x) >> 6;
    const unsigned lane = threadIdx.x & 63;
    const unsigned grp  = lane >> 4;      // edge-in-quad
    const unsigned co   = lane & 15;      // 16B chunk (8 bf16)
    if (wid >= (unsigned)N) {
        if (wid < (unsigned)NPAD && lane < 16)
            *reinterpret_cast<bf16x8*>(&aggb[(size_t)wid * FIN + co * 8]) =
                (bf16x8){0, 0, 0, 0, 0, 0, 0, 0};
        return;
    }
    const unsigned cv  = cnt[wid];
    const unsigned deg = min(cv, (unsigned)CAP);
    const int eid = (lane < deg) ? buck[(size_t)wid * CAP + lane] : 0;

    float acc[8];
#pragma unroll
    for (int q = 0; q < 8; ++q) acc[q] = 0.f;

    unsigned j = 0;
    for (; j + 8 <= deg; j += 8) {
        const int s0 = __shfl(eid, (int)(j + grp), 64);
        const int s1 = __shfl(eid, (int)(j + 4 + grp), 64);
        const bf16x8 v0 = *reinterpret_cast<const bf16x8*>(&xb[(size_t)s0 * FIN + co * 8]);
        const bf16x8 v1 = *reinterpret_cast<const bf16x8*>(&xb[(size_t)s1 * FIN + co * 8]);
#pragma unroll
        for (int q = 0; q < 8; ++q) acc[q] += bf2f((unsigned short)v0[q]);
#pragma unroll
        for (int q = 0; q < 8; ++q) acc[q] += bf2f((unsigned short)v1[q]);
    }
    if (j < deg) {                        // tail: up to 7 edges, 2 guarded loads
        const int s0 = __shfl(eid, (int)(j + grp), 64);          // j+grp   <= 63
        const int s1 = __shfl(eid, (int)(j + 4 + grp), 64);      // j+4+grp <= 63
        if (j + grp < deg) {
            const bf16x8 v0 = *reinterpret_cast<const bf16x8*>(&xb[(size_t)s0 * FIN + co * 8]);
#pragma unroll
            for (int q = 0; q < 8; ++q) acc[q] += bf2f((unsigned short)v0[q]);
        }
        if (j + 4 + grp < deg) {
            const bf16x8 v1 = *reinterpret_cast<const bf16x8*>(&xb[(size_t)s1 * FIN + co * 8]);
#pragma unroll
            for (int q = 0; q < 8; ++q) acc[q] += bf2f((unsigned short)v1[q]);
        }
    }

    // reduce across the 4 edge-groups (lanes l, l^16, l^32, l^48)
#pragma unroll
    for (int q = 0; q < 8; ++q) {
        acc[q] += __shfl_xor(acc[q], 16, 64);
        acc[q] += __shfl_xor(acc[q], 32, 64);
    }

    if (lane < 16) {
        const float sc = 1.0f / fmaxf((float)cv, 1.0f);
        bf16x8 o;
#pragma unroll
        for (int q = 0; q < 8; ++q) o[q] = (short)f2bf(acc[q] * sc);
        *reinterpret_cast<bf16x8*>(&aggb[(size_t)wid * FIN + co * 8]) = o;
    }
}

// ---------------------------------------------------------------------------
// Fused layer-1 GEMM + layer-2 pre-multiply, 64x256 tile, 256 threads.
// h1 never touches global memory.
// ---------------------------------------------------------------------------
__global__ __launch_bounds__(256) void k_l1m(const unsigned short* __restrict__ aggb,
                                             const unsigned short* __restrict__ xb,
                                             const unsigned short* __restrict__ Wlp,
                                             const unsigned short* __restrict__ Wrp,
                                             const unsigned short* __restrict__ Wc2p,
                                             const float* __restrict__ b1,
                                             float* __restrict__ y2,
                                             float* __restrict__ z2) {
    __shared__ short sA[2][64 * FIN];     // 32 KB; reused as sH[64][256] in stage 2
    short* sH = &sA[0][0];
    const int t = threadIdx.x;
    const int wave = t >> 6, lane = t & 63;
    const int g = lane >> 4, lr = lane & 15;
    const size_t row0 = (size_t)blockIdx.x * 64;

    for (int mat = 0; mat < 2; ++mat) {
        const unsigned short* src = mat ? xb : aggb;
        for (int i = t; i < 64 * 16; i += 256) {
            int r = i >> 4, c = i & 15;
            bf16x8 v = *reinterpret_cast<const bf16x8*>(&src[(row0 + r) * FIN + c * 8]);
            int dc = c ^ (r & 7);
            *reinterpret_cast<bf16x8*>(&sA[mat][r * FIN + dc * 8]) = v;
        }
    }
    __syncthreads();

    f32x4 acc[4][4];
#pragma unroll
    for (int m = 0; m < 4; ++m)
#pragma unroll
        for (int n = 0; n < 4; ++n) acc[m][n] = (f32x4){0.f, 0.f, 0.f, 0.f};

#pragma unroll
    for (int kk = 0; kk < 4; ++kk) {
        bf16x8 bL[4], bR[4];
#pragma unroll
        for (int n = 0; n < 4; ++n) {
            int col = wave * 64 + n * 16 + lr;
            size_t off = ((size_t)(kk * 256 + col) * 4 + g) * 8;
            bL[n] = *reinterpret_cast<const bf16x8*>(&Wlp[off]);
            bR[n] = *reinterpret_cast<const bf16x8*>(&Wrp[off]);
        }
        bf16x8 aA[4], aX[4];
        const int chunk = (kk * 4 + g) ^ (lr & 7);
#pragma unroll
        for (int m = 0; m < 4; ++m) {
            int r = m * 16 + lr;
            aA[m] = *reinterpret_cast<const bf16x8*>(&sA[0][r * FIN + chunk * 8]);
            aX[m] = *reinterpret_cast<const bf16x8*>(&sA[1][r * FIN + chunk * 8]);
        }
#pragma unroll
        for (int m = 0; m < 4; ++m)
#pragma unroll
            for (int n = 0; n < 4; ++n) {
                acc[m][n] = __builtin_amdgcn_mfma_f32_16x16x32_bf16(aA[m], bL[n], acc[m][n], 0, 0, 0);
                acc[m][n] = __builtin_amdgcn_mfma_f32_16x16x32_bf16(aX[m], bR[n], acc[m][n], 0, 0, 0);
            }
    }

    // stage 1 -> LDS: relu(acc+b1) as bf16, swizzled 16B chunks.
    __syncthreads();   // sA reads done in all waves
#pragma unroll
    for (int n = 0; n < 4; ++n) {
        int col = wave * 64 + n * 16 + lr;      // col&7 == lr&7
        float bb = b1[col];
        int c = col >> 3;
#pragma unroll
        for (int m = 0; m < 4; ++m) {
#pragma unroll
            for (int reg = 0; reg < 4; ++reg) {
                int r = m * 16 + g * 4 + reg;
                float z = fmaxf(acc[m][n][reg] + bb, 0.f);
                sH[r * HID + (c ^ (r & 7)) * 8 + (col & 7)] = (short)f2bf(z);
            }
        }
    }
    __syncthreads();

    // stage 2: rows [16*wave, 16*wave+16); k = 256; cols 0-15 Y, 16-31 Z.
    f32x4 accY = (f32x4){0.f, 0.f, 0.f, 0.f};
    f32x4 accZ = (f32x4){0.f, 0.f, 0.f, 0.f};
#pragma unroll
    for (int kk = 0; kk < 8; ++kk) {
        const int row = wave * 16 + lr;         // row&7 == lr&7
        const int dc = (kk * 4 + g) ^ (lr & 7);
        bf16x8 a  = *reinterpret_cast<const bf16x8*>(&sH[row * HID + dc * 8]);
        bf16x8 bY = *reinterpret_cast<const bf16x8*>(&Wc2p[((kk * 32u + lr) * 4u + g) * 8u]);
        bf16x8 bZ = *reinterpret_cast<const bf16x8*>(&Wc2p[((kk * 32u + 16u + lr) * 4u + g) * 8u]);
        accY = __builtin_amdgcn_mfma_f32_16x16x32_bf16(a, bY, accY, 0, 0, 0);
        accZ = __builtin_amdgcn_mfma_f32_16x16x32_bf16(a, bZ, accZ, 0, 0, 0);
    }
#pragma unroll
    for (int reg = 0; reg < 4; ++reg) {
        size_t r = row0 + wave * 16 + g * 4 + reg;
        y2[r * NC + lr] = accY[reg];
        z2[r * NC + lr] = accZ[reg];
    }
}

// ---------------------------------------------------------------------------
// out = log_softmax(gather(y2)/deg + z2 + b2); 16 lanes per node.
// Bucket ids, 16-wide coalesced; y2 row loads issued 8/4-deep.
// ---------------------------------------------------------------------------
__global__ __launch_bounds__(256) void k_out2(const float* __restrict__ y2,
                                              const float* __restrict__ z2,
                                              const int* __restrict__ buck,
                                              const unsigned* __restrict__ cnt,
                                              const float* __restrict__ b,
                                              float* __restrict__ out) {
    const int t = threadIdx.x, c = t & 15, nl = t >> 4;
    const int lbase = (nl & 3) * 16;          // lane offset of this 16-group in wave
    const size_t n = (size_t)blockIdx.x * 16 + nl;
    const unsigned cv  = cnt[n];
    const unsigned deg = min(cv, (unsigned)CAP);
    float gsum = 0.f;

    for (unsigned base = 0; base < deg; base += 16) {
        const unsigned cc = min(16u, deg - base);
        const int eid = ((unsigned)c < cc) ? buck[n * CAP + base + c] : 0;
        unsigned j = 0;
        for (; j + 8 <= cc; j += 8) {
            int s[8];
#pragma unroll
            for (int q = 0; q < 8; ++q) s[q] = __shfl(eid, lbase + (int)j + q, 64);
            float gv[8];
#pragma unroll
            for (int q = 0; q < 8; ++q) gv[q] = y2[(size_t)s[q] * NC + c];
#pragma unroll
            for (int q = 0; q < 8; ++q) gsum += gv[q];
        }
        for (; j + 4 <= cc; j += 4) {
            int s[4];
#pragma unroll
            for (int q = 0; q < 4; ++q) s[q] = __shfl(eid, lbase + (int)j + q, 64);
            float gv[4];
#pragma unroll
            for (int q = 0; q < 4; ++q) gv[q] = y2[(size_t)s[q] * NC + c];
#pragma unroll
            for (int q = 0; q < 4; ++q) gsum += gv[q];
        }
        for (; j < cc; ++j) {
            const int s = __shfl(eid, lbase + (int)j, 64);
            gsum += y2[(size_t)s * NC + c];
        }
    }
    const float sc = 1.0f / fmaxf((float)cv, 1.0f);
    float z = gsum * sc + z2[n * NC + c] + b[c];

    float m = z;
    for (int off = 1; off < 16; off <<= 1)
        m = fmaxf(m, __shfl_xor(m, off, 16));
    float ex = expf(z - m);
    float s = ex;
    for (int off = 1; off < 16; off <<= 1)
        s += __shfl_xor(s, off, 16);
    out[n * NC + c] = (z - m) - logf(s);
}

// ---------------------------------------------------------------------------
extern "C" void kernel_launch(void* const* d_in, const int* in_sizes, int n_in,
                              void* d_out, int out_size, void* d_ws, size_t ws_size,
                              hipStream_t stream) {
    const float* x    = (const float*)d_in[0];
    const int*   ei   = (const int*)d_in[1];    // int32 on device (JAX x64 off)
    const int*   srcv = ei;
    const int*   dstv = ei + NE;
    const float* W1l  = (const float*)d_in[2];
    const float* W1r  = (const float*)d_in[3];
    const float* b1   = (const float*)d_in[4];
    const float* W2l  = (const float*)d_in[5];
    const float* W2r  = (const float*)d_in[6];
    const float* b2   = (const float*)d_in[7];
    float* out = (float*)d_out;

    // workspace layout (float offsets; bf16x8 users 16B-aligned)
    float*          ws   = (float*)d_ws;
    unsigned*       cnt  = (unsigned*)ws;                    //    50,000
    int*            buck = (int*)(ws + 50000);               // 3,200,000 (N*CAP)
    unsigned short* xb   = (unsigned short*)(ws + 3250000);  // NPAD*128 bf16 = 3,203,072 f
    unsigned short* aggb = (unsigned short*)(ws + 6453072);  // NPAD*128 bf16
    unsigned short* Wlp  = (unsigned short*)(ws + 9656144);  // 32768 bf16 = 16,384 f
    unsigned short* Wrp  = (unsigned short*)(ws + 9672528);  // 32768 bf16
    unsigned short* Wc2p = (unsigned short*)(ws + 9688912);  //  8192 bf16 =  4,096 f
    float*          y2   = ws + 9693008;                     // NPAD*16 = 800,768
    float*          z2   = ws + 10493776;                    // NPAD*16 = 800,768
    // total: 11,294,544 floats = 45.2 MB

    const int EB = (NE + 255) / 256;
    k_prep  <<<CASTB + 232, 256, 0, stream>>>(x, xb, W1l, W1r, W2l, W2r,
                                              Wlp, Wrp, Wc2p, cnt);
    k_bucket<<<EB, 256, 0, stream>>>(srcv, dstv, cnt, buck);
    k_agg1  <<<(NPAD * 64) / 256, 256, 0, stream>>>(xb, buck, cnt, aggb);
    k_l1m   <<<NPAD / 64, 256, 0, stream>>>(aggb, xb, Wlp, Wrp, Wc2p, b1, y2, z2);
    k_out2  <<<N / 16, 256, 0, stream>>>(y2, z2, buck, cnt, b2, out);
}